// Round 1
// baseline (1007.917 us; speedup 1.0000x reference)
//
#include <hip/hip_runtime.h>
#include <hip/hip_bf16.h>
#include <stdint.h>

// Problem constants (fixed by the reference setup_inputs):
#define M_DIM 4096
#define N_DIM 8192   // O
#define K_DIM 8192   // I
#define NB    256    // K/32 Q4_0 blocks per row

#define BM 128
#define BN 128
#define BK 64

typedef __attribute__((ext_vector_type(8))) __bf16 bf16x8;
typedef __attribute__((ext_vector_type(4))) float floatx4;
typedef __attribute__((ext_vector_type(8))) unsigned short ushort8;

__device__ __forceinline__ unsigned short f32_to_bf16_rne(float f) {
    union { float f; unsigned int u; } v; v.f = f;
    unsigned int u = v.u;
    u += 0x7FFFu + ((u >> 16) & 1u);
    return (unsigned short)(u >> 16);
}

// ---------------- dequant: qweight[O,NB,16] int32-bytes + scales[O,NB] -> W bf16 [N,K] ----
__global__ __launch_bounds__(256) void dequant_w(const int* __restrict__ q,
                                                 const float* __restrict__ sc,
                                                 unsigned short* __restrict__ w) {
    int blk = blockIdx.x * 256 + threadIdx.x;   // one Q4_0 block per thread
    const int o = blk >> 8;        // NB == 256
    const int b = blk & 255;
    const int4* qp = (const int4*)(q + (size_t)blk * 16);
    int4 q0 = qp[0], q1 = qp[1], q2 = qp[2], q3 = qp[3];
    float s = sc[blk];
    int by[16];
    by[0]=q0.x; by[1]=q0.y; by[2]=q0.z; by[3]=q0.w;
    by[4]=q1.x; by[5]=q1.y; by[6]=q1.z; by[7]=q1.w;
    by[8]=q2.x; by[9]=q2.y; by[10]=q2.z; by[11]=q2.w;
    by[12]=q3.x; by[13]=q3.y; by[14]=q3.z; by[15]=q3.w;
    unsigned short out[32];
#pragma unroll
    for (int j = 0; j < 16; ++j) {
        int lo = (by[j] & 0xF) - 8;
        int hi = ((by[j] >> 4) & 0xF) - 8;
        out[j]      = f32_to_bf16_rne((float)lo * s);
        out[16 + j] = f32_to_bf16_rne((float)hi * s);
    }
    uint4* dst = (uint4*)(w + (size_t)o * K_DIM + b * 32);
    const uint4* srcv = (const uint4*)out;
    dst[0] = srcv[0]; dst[1] = srcv[1]; dst[2] = srcv[2]; dst[3] = srcv[3];
}

// ---------------- x fp32 -> bf16 ----------------
__global__ __launch_bounds__(256) void convert_x(const float* __restrict__ x,
                                                 unsigned short* __restrict__ xb) {
    size_t idx = ((size_t)blockIdx.x * 256 + threadIdx.x) * 8;
    float4 f0 = *(const float4*)(x + idx);
    float4 f1 = *(const float4*)(x + idx + 4);
    ushort8 o;
    o[0] = f32_to_bf16_rne(f0.x); o[1] = f32_to_bf16_rne(f0.y);
    o[2] = f32_to_bf16_rne(f0.z); o[3] = f32_to_bf16_rne(f0.w);
    o[4] = f32_to_bf16_rne(f1.x); o[5] = f32_to_bf16_rne(f1.y);
    o[6] = f32_to_bf16_rne(f1.z); o[7] = f32_to_bf16_rne(f1.w);
    *(ushort8*)(xb + idx) = o;
}

// ---------------- GEMM: C[M,N] = A[M,K] * B[N,K]^T + bias ----------------
__device__ __forceinline__ void load_lds16(const unsigned short* g, unsigned short* l) {
    __builtin_amdgcn_global_load_lds(
        (const __attribute__((address_space(1))) unsigned int*)(g),
        (__attribute__((address_space(3))) unsigned int*)(l),
        16, 0, 0);
}

__global__ __launch_bounds__(256) void gemm_bt(const unsigned short* __restrict__ A,
                                               const unsigned short* __restrict__ B,
                                               const float* __restrict__ bias,
                                               float* __restrict__ C) {
    // LDS tiles, row-major [128][64] bf16, columns XOR-swizzled:
    // LDS(row, c_phys) holds global(row, c_phys ^ (row & 7)) where c = 8-element group index.
    __shared__ unsigned short lsA[BM * BK];
    __shared__ unsigned short lsB[BN * BK];

    const int tid  = threadIdx.x;
    const int wave = tid >> 6;
    const int lane = tid & 63;
    const int wm = wave >> 1;   // 0..1 : 64-row stripe
    const int wn = wave & 1;    // 0..1 : 64-col stripe

    const int m0 = blockIdx.y * BM;
    const int n0 = blockIdx.x * BN;

    // Staging: each wave stages 32 rows of A and B (4 instructions each, 8 rows/instr).
    // lane i covers (row = i>>3, col8 = (i&7) ^ (i>>3))  -> LDS dest lane-sequential.
    const int srow  = wave * 32 + (lane >> 3);
    const int scol8 = (lane & 7) ^ (lane >> 3);
    const unsigned short* gA = A + (size_t)(m0 + srow) * K_DIM + scol8 * 8;
    const unsigned short* gB = B + (size_t)(n0 + srow) * K_DIM + scol8 * 8;
    unsigned short* dA = lsA + (wave * 32) * BK;  // wave-uniform base; HW adds lane*16B
    unsigned short* dB = lsB + (wave * 32) * BK;

    // Fragment LDS offsets (elements), constant across K-loop.
    // A-operand: A[m = lane&15][k = (lane>>4)*8 + j]; swizzled col group = (kk*4+q) ^ (lane&7)
    const int q   = lane >> 4;
    const int r15 = lane & 15;
    int aoff[2][4], boff[2][4];
#pragma unroll
    for (int kk = 0; kk < 2; ++kk) {
#pragma unroll
        for (int t = 0; t < 4; ++t) {
            int cphys = ((kk * 4 + q) ^ (lane & 7)) * 8;
            aoff[kk][t] = (wm * 64 + t * 16 + r15) * BK + cphys;
            boff[kk][t] = (wn * 64 + t * 16 + r15) * BK + cphys;
        }
    }

    floatx4 acc[4][4] = {};

    for (int kb = 0; kb < K_DIM / BK; ++kb) {
        const unsigned short* pA = gA + kb * BK;
        const unsigned short* pB = gB + kb * BK;
#pragma unroll
        for (int t = 0; t < 4; ++t) {
            load_lds16(pA + (size_t)t * 8 * K_DIM, dA + t * 8 * BK);
            load_lds16(pB + (size_t)t * 8 * K_DIM, dB + t * 8 * BK);
        }
        __syncthreads();
#pragma unroll
        for (int kk = 0; kk < 2; ++kk) {
            bf16x8 af[4], bfr[4];
#pragma unroll
            for (int t = 0; t < 4; ++t) {
                af[t]  = *(const bf16x8*)(lsA + aoff[kk][t]);
                bfr[t] = *(const bf16x8*)(lsB + boff[kk][t]);
            }
#pragma unroll
            for (int i = 0; i < 4; ++i)
#pragma unroll
                for (int j = 0; j < 4; ++j)
                    acc[i][j] = __builtin_amdgcn_mfma_f32_16x16x32_bf16(af[i], bfr[j], acc[i][j], 0, 0, 0);
        }
        __syncthreads();
    }

    // Epilogue: C/D layout col = lane&15, row = (lane>>4)*4 + reg
    const int colb = n0 + wn * 64 + r15;
    const int rowb = m0 + wm * 64 + q * 4;
#pragma unroll
    for (int j = 0; j < 4; ++j) {
        float bv = bias[colb + j * 16];
#pragma unroll
        for (int i = 0; i < 4; ++i) {
#pragma unroll
            for (int r = 0; r < 4; ++r) {
                C[(size_t)(rowb + i * 16 + r) * N_DIM + colb + j * 16] = acc[i][j][r] + bv;
            }
        }
    }
}

extern "C" void kernel_launch(void* const* d_in, const int* in_sizes, int n_in,
                              void* d_out, int out_size, void* d_ws, size_t ws_size,
                              hipStream_t stream) {
    (void)in_sizes; (void)n_in; (void)out_size; (void)ws_size;
    const float* x    = (const float*)d_in[0];
    const int*   qw   = (const int*)d_in[1];
    const float* sc   = (const float*)d_in[2];
    const float* bias = (const float*)d_in[3];
    float* out = (float*)d_out;

    unsigned short* Wb = (unsigned short*)d_ws;                                   // 128 MiB
    unsigned short* Xb = (unsigned short*)((char*)d_ws + (size_t)N_DIM * K_DIM * 2); // +64 MiB

    dequant_w<<<dim3((N_DIM * NB) / 256), dim3(256), 0, stream>>>(qw, sc, Wb);
    convert_x<<<dim3((size_t)M_DIM * K_DIM / (256 * 8)), dim3(256), 0, stream>>>(x, Xb);
    gemm_bt<<<dim3(N_DIM / BN, M_DIM / BM), dim3(256), 0, stream>>>(Xb, Wb, bias, out);
}

// Round 2
// 868.039 us; speedup vs baseline: 1.1611x; 1.1611x over previous
//
#include <hip/hip_runtime.h>
#include <hip/hip_bf16.h>
#include <stdint.h>

// Problem constants (fixed by the reference setup_inputs):
#define M_DIM 4096
#define N_DIM 8192   // O
#define K_DIM 8192   // I
#define NB    256    // K/32 Q4_0 blocks per row

#define BM 128
#define BN 256
#define BK 64

typedef __attribute__((ext_vector_type(8)))  __bf16 bf16x8;
typedef __attribute__((ext_vector_type(16))) float  floatx16;
typedef __attribute__((ext_vector_type(4)))  unsigned short ushort4v;
typedef __attribute__((ext_vector_type(8)))  unsigned short ushort8;

__device__ __forceinline__ unsigned short f32_to_bf16_rne(float f) {
    union { float f; unsigned int u; } v; v.f = f;
    unsigned int u = v.u;
    u += 0x7FFFu + ((u >> 16) & 1u);
    return (unsigned short)(u >> 16);
}

// ---- dequant: qweight[O,NB,16] int32-bytes + scales[O,NB] -> W bf16 [N,K] ----
// One thread per 4 consecutive int32 payload bytes (one int4 load, coalesced),
// producing 4 low-nibble + 4 high-nibble bf16 outputs (two 8B stores).
__global__ __launch_bounds__(256) void dequant_w(const int* __restrict__ q,
                                                 const float* __restrict__ sc,
                                                 unsigned short* __restrict__ w) {
    const int tid = blockIdx.x * 256 + threadIdx.x;   // 0 .. O*NB*4-1
    int4 v = ((const int4*)q)[tid];
    const int blk = tid >> 2;      // Q4_0 block index (o*NB + b)
    const int s   = tid & 3;       // 4-byte sub-chunk within block
    const float scale = sc[blk];
    int by[4] = { v.x, v.y, v.z, v.w };
    ushort4v lo, hi;
#pragma unroll
    for (int j = 0; j < 4; ++j) {
        lo[j] = f32_to_bf16_rne((float)((by[j] & 0xF) - 8) * scale);
        hi[j] = f32_to_bf16_rne((float)(((by[j] >> 4) & 0xF) - 8) * scale);
    }
    unsigned short* base = w + (size_t)blk * 32 + s * 4;
    *(ushort4v*)(base)      = lo;
    *(ushort4v*)(base + 16) = hi;
}

// ---------------- x fp32 -> bf16 ----------------
__global__ __launch_bounds__(256) void convert_x(const float* __restrict__ x,
                                                 unsigned short* __restrict__ xb) {
    size_t idx = ((size_t)blockIdx.x * 256 + threadIdx.x) * 8;
    float4 f0 = *(const float4*)(x + idx);
    float4 f1 = *(const float4*)(x + idx + 4);
    ushort8 o;
    o[0] = f32_to_bf16_rne(f0.x); o[1] = f32_to_bf16_rne(f0.y);
    o[2] = f32_to_bf16_rne(f0.z); o[3] = f32_to_bf16_rne(f0.w);
    o[4] = f32_to_bf16_rne(f1.x); o[5] = f32_to_bf16_rne(f1.y);
    o[6] = f32_to_bf16_rne(f1.z); o[7] = f32_to_bf16_rne(f1.w);
    *(ushort8*)(xb + idx) = o;
}

// ---------------- GEMM: C[M,N] = A[M,K] * B[N,K]^T + bias ----------------
// Block tile 128x256, BK=64. 4 waves in 2x2; wave tile 64x128 = 2x4 of 32x32
// MFMA tiles (v_mfma_f32_32x32x16_bf16). LDS columns XOR-swizzled by row&7.
__device__ __forceinline__ void load_lds16(const unsigned short* g, unsigned short* l) {
    __builtin_amdgcn_global_load_lds(
        (const __attribute__((address_space(1))) unsigned int*)(g),
        (__attribute__((address_space(3))) unsigned int*)(l),
        16, 0, 0);
}

__global__ __launch_bounds__(256, 2) void gemm_bt(const unsigned short* __restrict__ A,
                                                  const unsigned short* __restrict__ B,
                                                  const float* __restrict__ bias,
                                                  float* __restrict__ C) {
    __shared__ unsigned short lsA[BM * BK];   // 16 KiB
    __shared__ unsigned short lsB[BN * BK];   // 32 KiB

    const int tid  = threadIdx.x;
    const int wave = tid >> 6;
    const int lane = tid & 63;
    const int wm = wave >> 1;   // 0..1 : 64-row stripe of M
    const int wn = wave & 1;    // 0..1 : 128-col stripe of N

    const int m0 = blockIdx.y * BM;
    const int n0 = blockIdx.x * BN;

    // Staging: wave stages A rows [w*32, w*32+32) (4 instr) and
    // B rows [w*64, w*64+64) (8 instr); 8 rows per instruction.
    // lane i covers (row+ = i>>3, col8 = (i&7) ^ (i>>3)); LDS dest lane-sequential.
    const int lrow  = lane >> 3;                 // 0..7
    const int scol8 = (lane & 7) ^ lrow;         // swizzled global col group
    const unsigned short* gA = A + (size_t)(m0 + wave * 32 + lrow) * K_DIM + scol8 * 8;
    const unsigned short* gB = B + (size_t)(n0 + wave * 64 + lrow) * K_DIM + scol8 * 8;
    unsigned short* dA = lsA + (wave * 32) * BK;  // wave-uniform base; HW adds lane*16B
    unsigned short* dB = lsB + (wave * 64) * BK;

    // Fragment LDS offsets (elements), constant across the K loop.
    // 32x32x16 A-operand: A[m = lane&31][k = (lane>>5)*8 + j]
    // swizzled col8 group = (kk*2 + (lane>>5)) ^ (row&7); row&7 == lane&7 here.
    const int q5  = lane >> 5;
    const int r31 = lane & 31;
    const int l7  = lane & 7;
    int aoff[4][2], boff[4][4];
#pragma unroll
    for (int kk = 0; kk < 4; ++kk) {
        const int cphys = ((kk * 2 + q5) ^ l7) * 8;
#pragma unroll
        for (int i = 0; i < 2; ++i)
            aoff[kk][i] = (wm * 64 + i * 32 + r31) * BK + cphys;
#pragma unroll
        for (int j = 0; j < 4; ++j)
            boff[kk][j] = (wn * 128 + j * 32 + r31) * BK + cphys;
    }

    floatx16 acc[2][4] = {};

    for (int kb = 0; kb < K_DIM / BK; ++kb) {
        const unsigned short* pA = gA + kb * BK;
        const unsigned short* pB = gB + kb * BK;
#pragma unroll
        for (int t = 0; t < 4; ++t)
            load_lds16(pA + (size_t)t * 8 * K_DIM, dA + t * 8 * BK);
#pragma unroll
        for (int t = 0; t < 8; ++t)
            load_lds16(pB + (size_t)t * 8 * K_DIM, dB + t * 8 * BK);
        __syncthreads();
#pragma unroll
        for (int kk = 0; kk < 4; ++kk) {
            bf16x8 af[2], bf[4];
#pragma unroll
            for (int i = 0; i < 2; ++i) af[i] = *(const bf16x8*)(lsA + aoff[kk][i]);
#pragma unroll
            for (int j = 0; j < 4; ++j) bf[j] = *(const bf16x8*)(lsB + boff[kk][j]);
#pragma unroll
            for (int i = 0; i < 2; ++i)
#pragma unroll
                for (int j = 0; j < 4; ++j)
                    acc[i][j] = __builtin_amdgcn_mfma_f32_32x32x16_bf16(af[i], bf[j], acc[i][j], 0, 0, 0);
        }
        __syncthreads();
    }

    // Epilogue. 32x32 C/D layout: col = lane&31, row = (reg&3) + 8*(reg>>2) + 4*(lane>>5)
#pragma unroll
    for (int j = 0; j < 4; ++j) {
        const int col = n0 + wn * 128 + j * 32 + r31;
        const float bv = bias[col];
#pragma unroll
        for (int i = 0; i < 2; ++i) {
            const int rowbase = m0 + wm * 64 + i * 32 + q5 * 4;
#pragma unroll
            for (int r = 0; r < 16; ++r) {
                const int row = rowbase + (r & 3) + 8 * (r >> 2);
                C[(size_t)row * N_DIM + col] = acc[i][j][r] + bv;
            }
        }
    }
}

extern "C" void kernel_launch(void* const* d_in, const int* in_sizes, int n_in,
                              void* d_out, int out_size, void* d_ws, size_t ws_size,
                              hipStream_t stream) {
    (void)in_sizes; (void)n_in; (void)out_size; (void)ws_size;
    const float* x    = (const float*)d_in[0];
    const int*   qw   = (const int*)d_in[1];
    const float* sc   = (const float*)d_in[2];
    const float* bias = (const float*)d_in[3];
    float* out = (float*)d_out;

    unsigned short* Wb = (unsigned short*)d_ws;                                      // 128 MiB
    unsigned short* Xb = (unsigned short*)((char*)d_ws + (size_t)N_DIM * K_DIM * 2); // +64 MiB

    dequant_w<<<dim3((N_DIM * NB * 4) / 256), dim3(256), 0, stream>>>(qw, sc, Wb);
    convert_x<<<dim3((size_t)M_DIM * K_DIM / (256 * 8)), dim3(256), 0, stream>>>(x, Xb);
    gemm_bt<<<dim3(N_DIM / BN, M_DIM / BM), dim3(256), 0, stream>>>(Xb, Wb, bias, out);
}

// Round 3
// 851.089 us; speedup vs baseline: 1.1843x; 1.0199x over previous
//
#include <hip/hip_runtime.h>
#include <hip/hip_bf16.h>
#include <stdint.h>

// Problem constants (fixed by the reference setup_inputs):
#define M_DIM 4096
#define N_DIM 8192   // O
#define K_DIM 8192   // I
#define NB    256    // K/32 Q4_0 blocks per row

#define BM 128
#define BN 256
#define BK 64

typedef __attribute__((ext_vector_type(8)))  __bf16 bf16x8;
typedef __attribute__((ext_vector_type(16))) float  floatx16;
typedef __attribute__((ext_vector_type(4)))  unsigned short ushort4v;
typedef __attribute__((ext_vector_type(8)))  unsigned short ushort8;

__device__ __forceinline__ unsigned short f32_to_bf16_rne(float f) {
    union { float f; unsigned int u; } v; v.f = f;
    unsigned int u = v.u;
    u += 0x7FFFu + ((u >> 16) & 1u);
    return (unsigned short)(u >> 16);
}

// ---- dequant: qweight[O,NB,16] int32-bytes + scales[O,NB] -> W bf16 [N,K] ----
__global__ __launch_bounds__(256) void dequant_w(const int* __restrict__ q,
                                                 const float* __restrict__ sc,
                                                 unsigned short* __restrict__ w) {
    const int tid = blockIdx.x * 256 + threadIdx.x;   // 0 .. O*NB*4-1
    int4 v = ((const int4*)q)[tid];
    const int blk = tid >> 2;      // Q4_0 block index (o*NB + b)
    const int s   = tid & 3;       // 4-byte sub-chunk within block
    const float scale = sc[blk];
    int by[4] = { v.x, v.y, v.z, v.w };
    ushort4v lo, hi;
#pragma unroll
    for (int j = 0; j < 4; ++j) {
        lo[j] = f32_to_bf16_rne((float)((by[j] & 0xF) - 8) * scale);
        hi[j] = f32_to_bf16_rne((float)(((by[j] >> 4) & 0xF) - 8) * scale);
    }
    unsigned short* base = w + (size_t)blk * 32 + s * 4;
    *(ushort4v*)(base)      = lo;
    *(ushort4v*)(base + 16) = hi;
}

// ---------------- x fp32 -> bf16 ----------------
__global__ __launch_bounds__(256) void convert_x(const float* __restrict__ x,
                                                 unsigned short* __restrict__ xb) {
    size_t idx = ((size_t)blockIdx.x * 256 + threadIdx.x) * 8;
    float4 f0 = *(const float4*)(x + idx);
    float4 f1 = *(const float4*)(x + idx + 4);
    ushort8 o;
    o[0] = f32_to_bf16_rne(f0.x); o[1] = f32_to_bf16_rne(f0.y);
    o[2] = f32_to_bf16_rne(f0.z); o[3] = f32_to_bf16_rne(f0.w);
    o[4] = f32_to_bf16_rne(f1.x); o[5] = f32_to_bf16_rne(f1.y);
    o[6] = f32_to_bf16_rne(f1.z); o[7] = f32_to_bf16_rne(f1.w);
    *(ushort8*)(xb + idx) = o;
}

// ---------------- GEMM: C[M,N] = A[M,K] * B[N,K]^T + bias ----------------
// Block tile 128x256, BK=64. 4 waves in 2x2; wave tile 64x128 = 2x4 of 32x32
// MFMA tiles. LDS column-group swizzle: LDS(row, cp) holds
// global(row, cp ^ f(row)) with f(row) = (row ^ (row>>3)) & 7  — varies with
// row bits 0..5 so lanes {l, l+8, l+16, l+24} (rows r, r+8, r+16, r+24) hit
// distinct bank groups within one ds_read_b128.
__device__ __forceinline__ void load_lds16(const unsigned short* g, unsigned short* l) {
    __builtin_amdgcn_global_load_lds(
        (const __attribute__((address_space(1))) unsigned int*)(g),
        (__attribute__((address_space(3))) unsigned int*)(l),
        16, 0, 0);
}

__global__ __launch_bounds__(256, 2) void gemm_bt(const unsigned short* __restrict__ A,
                                                  const unsigned short* __restrict__ B,
                                                  const float* __restrict__ bias,
                                                  float* __restrict__ C) {
    __shared__ unsigned short lsA[BM * BK];   // 16 KiB
    __shared__ unsigned short lsB[BN * BK];   // 32 KiB

    const int tid  = threadIdx.x;
    const int wave = tid >> 6;
    const int lane = tid & 63;
    const int wm = wave >> 1;   // 0..1 : 64-row stripe of M
    const int wn = wave & 1;    // 0..1 : 128-col stripe of N

    const int m0 = blockIdx.y * BM;
    const int n0 = blockIdx.x * BN;

    // Staging: wave stages A rows [w*32, w*32+32) (4 instr) and
    // B rows [w*64, w*64+64) (8 instr); 8 rows per instruction.
    // Within instr t, row = base_t + lrow, (row>>3)&7 is constant -> fold the
    // row-octet part of f into the per-instruction source column.
    const int lrow = lane >> 3;                 // 0..7
    const int l7s  = lane & 7;
    const unsigned short* gAr = A + (size_t)(m0 + wave * 32 + lrow) * K_DIM;
    const unsigned short* gBr = B + (size_t)(n0 + wave * 64 + lrow) * K_DIM;
    unsigned short* dA = lsA + (wave * 32) * BK;  // wave-uniform base; HW adds lane*16B
    unsigned short* dB = lsB + (wave * 64) * BK;
    int caoff[4], cboff[8];
#pragma unroll
    for (int t = 0; t < 4; ++t)
        caoff[t] = (l7s ^ lrow ^ ((wave * 4 + t) & 7)) * 8;   // A: row>>3 = wave*4+t
#pragma unroll
    for (int t = 0; t < 8; ++t)
        cboff[t] = (l7s ^ lrow ^ t) * 8;                       // B: (row>>3)&7 = t

    // Fragment LDS offsets (elements), constant across the K loop.
    // 32x32x16 A-operand: A[m = lane&31][k = (lane>>5)*8 + j]
    const int q5  = lane >> 5;
    const int r31 = lane & 31;
    const int l7  = lane & 7;
    const int rh  = r31 >> 3;   // 0..3
    int aoff[4][2], boff[4][4];
#pragma unroll
    for (int kk = 0; kk < 4; ++kk) {
#pragma unroll
        for (int i = 0; i < 2; ++i) {
            const int f = l7 ^ ((i * 4 + rh) & 7);
            aoff[kk][i] = (wm * 64 + i * 32 + r31) * BK + ((kk * 2 + q5) ^ f) * 8;
        }
#pragma unroll
        for (int j = 0; j < 4; ++j) {
            const int f = l7 ^ ((j * 4 + rh) & 7);
            boff[kk][j] = (wn * 128 + j * 32 + r31) * BK + ((kk * 2 + q5) ^ f) * 8;
        }
    }

    floatx16 acc[2][4] = {};

    for (int kb = 0; kb < K_DIM / BK; ++kb) {
        const unsigned short* pA = gAr + kb * BK;
        const unsigned short* pB = gBr + kb * BK;
#pragma unroll
        for (int t = 0; t < 4; ++t)
            load_lds16(pA + (size_t)t * 8 * K_DIM + caoff[t], dA + t * 8 * BK);
#pragma unroll
        for (int t = 0; t < 8; ++t)
            load_lds16(pB + (size_t)t * 8 * K_DIM + cboff[t], dB + t * 8 * BK);
        __syncthreads();
#pragma unroll
        for (int kk = 0; kk < 4; ++kk) {
            bf16x8 af[2], bf[4];
#pragma unroll
            for (int i = 0; i < 2; ++i) af[i] = *(const bf16x8*)(lsA + aoff[kk][i]);
#pragma unroll
            for (int j = 0; j < 4; ++j) bf[j] = *(const bf16x8*)(lsB + boff[kk][j]);
#pragma unroll
            for (int i = 0; i < 2; ++i)
#pragma unroll
                for (int j = 0; j < 4; ++j)
                    acc[i][j] = __builtin_amdgcn_mfma_f32_32x32x16_bf16(af[i], bf[j], acc[i][j], 0, 0, 0);
        }
        __syncthreads();
    }

    // Epilogue. 32x32 C/D layout: col = lane&31, row = (reg&3) + 8*(reg>>2) + 4*(lane>>5)
#pragma unroll
    for (int j = 0; j < 4; ++j) {
        const int col = n0 + wn * 128 + j * 32 + r31;
        const float bv = bias[col];
#pragma unroll
        for (int i = 0; i < 2; ++i) {
            const int rowbase = m0 + wm * 64 + i * 32 + q5 * 4;
#pragma unroll
            for (int r = 0; r < 16; ++r) {
                const int row = rowbase + (r & 3) + 8 * (r >> 2);
                C[(size_t)row * N_DIM + col] = acc[i][j][r] + bv;
            }
        }
    }
}

extern "C" void kernel_launch(void* const* d_in, const int* in_sizes, int n_in,
                              void* d_out, int out_size, void* d_ws, size_t ws_size,
                              hipStream_t stream) {
    (void)in_sizes; (void)n_in; (void)out_size; (void)ws_size;
    const float* x    = (const float*)d_in[0];
    const int*   qw   = (const int*)d_in[1];
    const float* sc   = (const float*)d_in[2];
    const float* bias = (const float*)d_in[3];
    float* out = (float*)d_out;

    unsigned short* Wb = (unsigned short*)d_ws;                                      // 128 MiB
    unsigned short* Xb = (unsigned short*)((char*)d_ws + (size_t)N_DIM * K_DIM * 2); // +64 MiB

    dequant_w<<<dim3((N_DIM * NB * 4) / 256), dim3(256), 0, stream>>>(qw, sc, Wb);
    convert_x<<<dim3((size_t)M_DIM * K_DIM / (256 * 8)), dim3(256), 0, stream>>>(x, Xb);
    gemm_bt<<<dim3(N_DIM / BN, M_DIM / BM), dim3(256), 0, stream>>>(Xb, Wb, bias, out);
}